// Round 4
// baseline (240.028 us; speedup 1.0000x reference)
//
#include <hip/hip_runtime.h>
#include <hip/hip_bf16.h>

// Problem constants (from reference): B=4, S=4096, D=2048, K=4
// x: [B,S,D] fp32, weight: [D,1,K] fp32, bias: [D] fp32, out: [B,S,D] fp32
// out[b,s,d] = bias[d] + sum_k w[d,k] * x[b, s-3+k, d]   (zero-pad s<0)

typedef float vfloat4 __attribute__((ext_vector_type(4)));  // native vec for builtins

namespace {
constexpr int B = 4;
constexpr int S = 4096;
constexpr int D = 2048;
constexpr int D4 = D / 4;        // 512 vfloat4 per row
constexpr int R = 16;            // s-rows per thread
constexpr int BLOCK = 256;
}

__global__ __launch_bounds__(BLOCK, 1) void causal_dwconv1d_k4(
    const vfloat4* __restrict__ x,      // [B*S*D4]
    const vfloat4* __restrict__ w4,     // [D] : w4[d] = {w[d,0..3]}
    const vfloat4* __restrict__ bias4,  // [D4]
    vfloat4* __restrict__ out)          // [B*S*D4]
{
    const int d4 = blockIdx.x * BLOCK + threadIdx.x;   // 0..D4-1
    const int s0 = blockIdx.y * R;
    const int b  = blockIdx.z;

    const vfloat4* xb = x   + (size_t)b * S * D4 + d4;
    vfloat4*       ob = out + (size_t)b * S * D4 + d4;

    const vfloat4 zero = (vfloat4)(0.f);

    // Weights first (L2-resident, returns come back early in-order).
    const vfloat4 wa = w4[d4 * 4 + 0];
    const vfloat4 wb = w4[d4 * 4 + 1];
    const vfloat4 wc = w4[d4 * 4 + 2];
    const vfloat4 wd = w4[d4 * 4 + 3];
    const vfloat4 bv = bias4[d4];

    // All R+3 = 19 x-row loads issued up-front. The sched_barrier(0) below
    // forbids the compiler from sinking any of these past it, forcing all
    // 19 global_load_dwordx4 to be in flight simultaneously (deep MLP).
    vfloat4 xr[R + 3];
    if (s0 >= 3) {
#pragma unroll
        for (int i = 0; i < R + 3; ++i)
            xr[i] = xb[(size_t)(s0 - 3 + i) * D4];
    } else {
#pragma unroll
        for (int i = 0; i < R + 3; ++i) {
            const int s = s0 - 3 + i;
            xr[i] = (s >= 0) ? xb[(size_t)s * D4] : zero;
        }
    }
    __builtin_amdgcn_sched_barrier(0);   // pin: loads above, compute below

#pragma unroll
    for (int r = 0; r < R; ++r) {
        const vfloat4 xm3 = xr[r + 0];
        const vfloat4 xm2 = xr[r + 1];
        const vfloat4 xm1 = xr[r + 2];
        const vfloat4 xc  = xr[r + 3];
        vfloat4 o;
        o.x = bv.x + wa.x * xm3.x + wa.y * xm2.x + wa.z * xm1.x + wa.w * xc.x;
        o.y = bv.y + wb.x * xm3.y + wb.y * xm2.y + wb.z * xm1.y + wb.w * xc.y;
        o.z = bv.z + wc.x * xm3.z + wc.y * xm2.z + wc.z * xm1.z + wc.w * xc.z;
        o.w = bv.w + wd.x * xm3.w + wd.y * xm2.w + wd.z * xm1.w + wd.w * xc.w;
        // Non-temporal store: out is write-once streaming.
        __builtin_nontemporal_store(o, &ob[(size_t)(s0 + r) * D4]);
    }
}

extern "C" void kernel_launch(void* const* d_in, const int* in_sizes, int n_in,
                              void* d_out, int out_size, void* d_ws, size_t ws_size,
                              hipStream_t stream) {
    const vfloat4* x     = (const vfloat4*)d_in[0];
    const vfloat4* w4    = (const vfloat4*)d_in[1];
    const vfloat4* bias4 = (const vfloat4*)d_in[2];
    vfloat4* out         = (vfloat4*)d_out;

    dim3 grid(D4 / BLOCK, S / R, B);   // (2, 256, 4) = 2048 blocks
    dim3 block(BLOCK);
    causal_dwconv1d_k4<<<grid, block, 0, stream>>>(x, w4, bias4, out);
}

// Round 6
// 235.520 us; speedup vs baseline: 1.0191x; 1.0191x over previous
//
#include <hip/hip_runtime.h>
#include <hip/hip_bf16.h>

// Problem constants (from reference): B=4, S=4096, D=2048, K=4
// x: [B,S,D] fp32, weight: [D,1,K] fp32, bias: [D] fp32, out: [B,S,D] fp32
// out[b,s,d] = bias[d] + sum_k w[d,k] * x[b, s-3+k, d]   (zero-pad s<0)
//
// R5 (resubmit — prior round hit GPUAcquisitionTimeout, never benched):
// block covers the FULL channel dim (512 threads = D4 columns), so each
// block's global footprint is one contiguous 152KB read + 128KB write region
// (x[b,s,:] rows are adjacent). Dense sequential streams per block instead of
// 2048x19 scattered 1KB-granule strided streams — copy-kernel access shape.

typedef float vfloat4 __attribute__((ext_vector_type(4)));

namespace {
constexpr int B = 4;
constexpr int S = 4096;
constexpr int D = 2048;
constexpr int D4 = D / 4;        // 512 vfloat4 per row
constexpr int R = 16;            // s-rows per block/thread
constexpr int BLOCK = 512;       // one thread per d4 column
}

__global__ __launch_bounds__(BLOCK) void causal_dwconv1d_k4(
    const vfloat4* __restrict__ x,      // [B*S*D4]
    const vfloat4* __restrict__ w4,     // [D] : w4[d] = {w[d,0..3]}
    const vfloat4* __restrict__ bias4,  // [D4]
    vfloat4* __restrict__ out)          // [B*S*D4]
{
    const int d4 = threadIdx.x;                 // 0..511
    const int s0 = blockIdx.x * R;
    const int b  = blockIdx.y;

    const vfloat4* xb = x   + (size_t)b * S * D4 + d4;
    vfloat4*       ob = out + (size_t)b * S * D4 + d4;

    const vfloat4 zero = (vfloat4)(0.f);

    // Per-channel weights (small, cache-resident).
    const vfloat4 wa = w4[d4 * 4 + 0];
    const vfloat4 wb = w4[d4 * 4 + 1];
    const vfloat4 wc = w4[d4 * 4 + 2];
    const vfloat4 wd = w4[d4 * 4 + 3];
    const vfloat4 bv = bias4[d4];

    // Prefetch all R+3 rows; block-aggregate access = contiguous 152KB.
    vfloat4 xr[R + 3];
    if (s0 >= 3) {
#pragma unroll
        for (int i = 0; i < R + 3; ++i)
            xr[i] = xb[(size_t)(s0 - 3 + i) * D4];
    } else {
#pragma unroll
        for (int i = 0; i < R + 3; ++i) {
            const int s = s0 - 3 + i;
            xr[i] = (s >= 0) ? xb[(size_t)s * D4] : zero;
        }
    }
    __builtin_amdgcn_sched_barrier(0);   // keep loads clustered ahead of compute

#pragma unroll
    for (int r = 0; r < R; ++r) {
        const vfloat4 xm3 = xr[r + 0];
        const vfloat4 xm2 = xr[r + 1];
        const vfloat4 xm1 = xr[r + 2];
        const vfloat4 xc  = xr[r + 3];
        vfloat4 o;
        o.x = bv.x + wa.x * xm3.x + wa.y * xm2.x + wa.z * xm1.x + wa.w * xc.x;
        o.y = bv.y + wb.x * xm3.y + wb.y * xm2.y + wb.z * xm1.y + wb.w * xc.y;
        o.z = bv.z + wc.x * xm3.z + wc.y * xm2.z + wc.z * xm1.z + wc.w * xc.z;
        o.w = bv.w + wd.x * xm3.w + wd.y * xm2.w + wd.z * xm1.w + wd.w * xc.w;
        __builtin_nontemporal_store(o, &ob[(size_t)(s0 + r) * D4]);
    }
}

extern "C" void kernel_launch(void* const* d_in, const int* in_sizes, int n_in,
                              void* d_out, int out_size, void* d_ws, size_t ws_size,
                              hipStream_t stream) {
    const vfloat4* x     = (const vfloat4*)d_in[0];
    const vfloat4* w4    = (const vfloat4*)d_in[1];
    const vfloat4* bias4 = (const vfloat4*)d_in[2];
    vfloat4* out         = (vfloat4*)d_out;

    dim3 grid(S / R, B);               // (256, 4) = 1024 blocks x 512 thr
    dim3 block(BLOCK);
    causal_dwconv1d_k4<<<grid, block, 0, stream>>>(x, w4, bias4, out);
}